// Round 20
// baseline (170.341 us; speedup 1.0000x reference)
//
#include <hip/hip_runtime.h>
#include <hip/hip_bf16.h>
#include <stdint.h>

// Problem constants
#define BB   4
#define SS   2048
#define DIN  1024
#define DOUT 1024
#define NH   16
#define HD   64
#define MROWS (BB * SS)   // 8192

typedef __bf16 bf16x8 __attribute__((ext_vector_type(8)));
typedef float  f32x4  __attribute__((ext_vector_type(4)));

__device__ __forceinline__ unsigned short f2bf(float f) {
  union { float f; uint32_t u; } v; v.f = f;
  uint32_t u = v.u;
  uint32_t r = (u + 0x7fffu + ((u >> 16) & 1u)) >> 16;
  return (unsigned short)r;
}

__device__ __forceinline__ unsigned int cvt_pk_bf16(float lo, float hi) {
  unsigned int r;
  asm("v_cvt_pk_bf16_f32 %0, %1, %2" : "=v"(r) : "v"(lo), "v"(hi));
  return r;
}

#define GLOAD_LDS16(gsrc, ldst)                                                   \
  __builtin_amdgcn_global_load_lds(                                               \
      (const __attribute__((address_space(1))) void*)(gsrc),                      \
      (__attribute__((address_space(3))) void*)(ldst), 16, 0, 0)

// ---------------- fused conversion kernel ----------------
// blocks [0,2048): x f32 -> bf16 (4 float4 per thread, coalesced)
// blocks [2048,6144): W transpose-convert, one 32x32 tile per block.
__global__ __launch_bounds__(256) void cvt_fused_kernel(
    const float* __restrict__ x,
    const float* __restrict__ w0, const float* __restrict__ w1,
    const float* __restrict__ w2, const float* __restrict__ w3,
    unsigned short* __restrict__ xb, unsigned short* __restrict__ wt) {
  __shared__ float tile[32][33];
  const int bx = blockIdx.x, tid = threadIdx.x;
  if (bx < 2048) {
    const float4* in4 = (const float4*)x;
    ushort4* out4 = (ushort4*)xb;
    int i = bx * 256 + tid;
#pragma unroll
    for (int r = 0; r < 4; ++r) {
      int idx = i + r * (2048 * 256);   // covers 2,097,152 float4 total
      float4 f = in4[idx];
      ushort4 o;
      o.x = f2bf(f.x); o.y = f2bf(f.y); o.z = f2bf(f.z); o.w = f2bf(f.w);
      out4[idx] = o;
    }
  } else {
    const int t = bx - 2048;          // 0..4095
    const int z = t >> 10;            // matrix 0..3
    const int tt = t & 1023;          // tile 0..1023
    const int kb = (tt & 31) * 32, nb = (tt >> 5) * 32;
    const float* src = (z == 0) ? w0 : (z == 1) ? w1 : (z == 2) ? w2 : w3;
    unsigned short* dst = wt + (size_t)z * (DIN * DOUT);
    const int row0 = tid >> 5, col = tid & 31;
#pragma unroll
    for (int r = 0; r < 4; ++r) {
      int row = row0 + r * 8;
      tile[row][col] = src[(size_t)(kb + row) * DOUT + nb + col];
    }
    __syncthreads();
#pragma unroll
    for (int r = 0; r < 4; ++r) {
      int row = row0 + r * 8;
      dst[(size_t)(nb + row) * DIN + kb + col] = f2bf(tile[col][row]);
    }
  }
}

// XCD-aware bijective remap for 512-block GEMM grids (8 XCDs, 512 = 8*64)
__device__ __forceinline__ void xcd_remap_512(int& nT, int& mT) {
  int orig = blockIdx.x + blockIdx.y * 8;
  int id = (orig & 7) * 64 + (orig >> 3);
  nT = id & 7;
  mT = id >> 3;
}

// ---------------- GEMM core: 128x128 tile, BK=32, dbuf 32KB, ~5 blocks/CU ---
// Co-residency pipelining (the only lever that has moved GEMMs here): smaller
// LDS footprint raises blocks/CU 2 -> 5 so sibling blocks hide each other's
// stage/drain windows. Geometry = round-5's measured-zero-conflict [128][32]
// swizzle (phys chunk = logical ^ ((row>>1)&3), source pre-XOR'd, linear
// global_load_lds dest) + round-8's stage-first/one-barrier loop.
__device__ __forceinline__ void gemm128_core(const unsigned short* __restrict__ A,
                                             const unsigned short* __restrict__ BT,
                                             f32x4 (&acc)[4][4]) {
  extern __shared__ __align__(16) unsigned short sm[];
  // A buf b at b*4096 elems; B buf b at 8192 + b*4096 (32 KB total)
  const int tid = threadIdx.x, lane = tid & 63, w = tid >> 6;
  const int wm = (w >> 1) * 64, wn = (w & 1) * 64;
  const int g = lane >> 4, c = lane & 15;

#pragma unroll
  for (int mi = 0; mi < 4; mi++)
#pragma unroll
    for (int ni = 0; ni < 4; ni++)
      acc[mi][ni] = (f32x4){0.f, 0.f, 0.f, 0.f};

  // staging: 2 calls/matrix/tile; call j covers rows j*64..+63.
  // thread -> row (tid>>2), chunk (tid&3); global chunk pre-XOR'd ((row>>1)&3)
  const int srow = tid >> 2;
  const int gchunk = (tid & 3) ^ ((srow >> 1) & 3);
  const unsigned short* Ag = A + (size_t)srow * 1024 + gchunk * 8;
  const unsigned short* Bg = BT + (size_t)srow * 1024 + gchunk * 8;
  const int dst8 = tid * 8;   // + j*2048 : linear LDS dest (elems)

#define STAGE32(kt, buf) do {                                               \
    const int _k = (kt) * 32;                                               \
    _Pragma("unroll") for (int _j = 0; _j < 2; ++_j) {                      \
      GLOAD_LDS16(Ag + (size_t)_j * 64 * 1024 + _k,                         \
                  &sm[(buf) * 4096 + _j * 2048 + dst8]);                    \
      GLOAD_LDS16(Bg + (size_t)_j * 64 * 1024 + _k,                         \
                  &sm[8192 + (buf) * 4096 + _j * 2048 + dst8]);             \
    } } while (0)

  // fragment reads: row r, phys chunk g ^ ((r>>1)&3) = g ^ ((c>>1)&3)
  const int rx = (c >> 1) & 3;
  int aoff[4], boff[4];
#pragma unroll
  for (int mi = 0; mi < 4; mi++)
    aoff[mi] = (wm + mi * 16 + c) * 32 + ((g ^ rx) * 8);
#pragma unroll
  for (int ni = 0; ni < 4; ni++)
    boff[ni] = (wn + ni * 16 + c) * 32 + ((g ^ rx) * 8);

  STAGE32(0, 0);
  __syncthreads();   // tile 0 resident

#pragma unroll 1
  for (int t = 0; t < 32; ++t) {
    const int buf = t & 1;
    if (t + 1 < 32) STAGE32(t + 1, buf ^ 1);   // issued first: max lead time
    const unsigned short* As_ = sm + buf * 4096;
    const unsigned short* Bs_ = sm + 8192 + buf * 4096;
    bf16x8 a[4], b[4];
#pragma unroll
    for (int mi = 0; mi < 4; mi++) a[mi] = *(const bf16x8*)&As_[aoff[mi]];
#pragma unroll
    for (int ni = 0; ni < 4; ni++) b[ni] = *(const bf16x8*)&Bs_[boff[ni]];
#pragma unroll
    for (int mi = 0; mi < 4; mi++)
#pragma unroll
      for (int ni = 0; ni < 4; ni++)
        acc[mi][ni] = __builtin_amdgcn_mfma_f32_16x16x32_bf16(a[mi], b[ni], acc[mi][ni], 0, 0, 0);
    __syncthreads();   // drains: tile t+1 resident, readers done
  }
#undef STAGE32
}

// QKV projection. z=0: Q (scaled log2e/8) -> [b][h][s][hd]; z=1: K; z=2: V^T [b][h][hd][s]
__global__ __launch_bounds__(256, 4) void gemm_qkv_kernel(
    const unsigned short* __restrict__ xb, const unsigned short* __restrict__ wt,
    unsigned short* __restrict__ qs, unsigned short* __restrict__ kbuf,
    unsigned short* __restrict__ vt) {
  int nT, mT;
  xcd_remap_512(nT, mT);
  const int z = blockIdx.z;
  f32x4 acc[4][4];
  gemm128_core(xb + (size_t)mT * 128 * 1024,
               wt + (size_t)z * (DIN * DOUT) + (size_t)nT * 128 * 1024, acc);

  const int tid = threadIdx.x, lane = tid & 63, w = tid >> 6;
  const int wm = (w >> 1) * 64, wn = (w & 1) * 64;
  const int g = lane >> 4, c = lane & 15;
  const float scale = (z == 0) ? 0.18033688011112042f : 1.0f;  // (1/8)*log2(e)

  if (z < 2) {
    unsigned short* dstQK = (z == 0) ? qs : kbuf;
#pragma unroll
    for (int mi = 0; mi < 4; mi++)
#pragma unroll
      for (int ni = 0; ni < 4; ni++) {
        int n = nT * 128 + wn + ni * 16 + c;
        int h = n >> 6, hd = n & 63;
#pragma unroll
        for (int jj = 0; jj < 4; jj++) {
          int m = mT * 128 + wm + mi * 16 + g * 4 + jj;
          int b = m >> 11, ss = m & 2047;
          dstQK[(((size_t)(b * NH + h)) * SS + ss) * HD + hd] = f2bf(acc[mi][ni][jj] * scale);
        }
      }
  } else {
#pragma unroll
    for (int mi = 0; mi < 4; mi++) {
      int m0 = mT * 128 + wm + mi * 16 + g * 4;
      int b = m0 >> 11, s0 = m0 & 2047;
#pragma unroll
      for (int ni = 0; ni < 4; ni++) {
        int n = nT * 128 + wn + ni * 16 + c;
        int h = n >> 6, hd = n & 63;
        uint2 st;
        st.x = cvt_pk_bf16(acc[mi][ni][0], acc[mi][ni][1]);
        st.y = cvt_pk_bf16(acc[mi][ni][2], acc[mi][ni][3]);
        *(uint2*)&vt[(((size_t)(b * NH + h)) * HD + hd) * SS + s0] = st;
      }
    }
  }
}

// Output projection: out = ctx @ Wp + bp (fp32 out)
__global__ __launch_bounds__(256, 4) void gemm_out_kernel(
    const unsigned short* __restrict__ ctx, const unsigned short* __restrict__ wtp,
    const float* __restrict__ bp, float* __restrict__ out) {
  int nT, mT;
  xcd_remap_512(nT, mT);
  f32x4 acc[4][4];
  gemm128_core(ctx + (size_t)mT * 128 * 1024, wtp + (size_t)nT * 128 * 1024, acc);

  const int tid = threadIdx.x, lane = tid & 63, w = tid >> 6;
  const int wm = (w >> 1) * 64, wn = (w & 1) * 64;
  const int g = lane >> 4, c = lane & 15;
#pragma unroll
  for (int mi = 0; mi < 4; mi++)
#pragma unroll
    for (int ni = 0; ni < 4; ni++) {
      int n = nT * 128 + wn + ni * 16 + c;
      float bias = bp[n];
#pragma unroll
      for (int jj = 0; jj < 4; jj++) {
        int m = mT * 128 + wm + mi * 16 + g * 4 + jj;
        out[(size_t)m * DOUT + n] = acc[mi][ni][jj] + bias;
      }
    }
}

// ---------------- flash attention: 8-wave blocks, 1 q-block each ------------
// ROUND-15 EXACT (field-proven: passed, 82 us, absmax 0.015625). FROZEN.
__global__ __launch_bounds__(512) void attn_kernel(
    const unsigned short* __restrict__ qs, const unsigned short* __restrict__ kbuf,
    const unsigned short* __restrict__ vt, unsigned short* __restrict__ ctx) {
  const int bx = blockIdx.x;
  const int xcd = bx & 7, j = bx >> 3;
  const int hb = xcd * 8 + (j & 7);
  const int h = hb & 15, b = hb >> 4;
  const int qtB = 7 - (j >> 3);

  const int tid = threadIdx.x, lane = tid & 63, w = tid >> 6;
  const int g = lane >> 4, c = lane & 15;
  const size_t bh = (size_t)(b * NH + h);
  const unsigned short* Q = qs + bh * SS * HD;
  const unsigned short* K = kbuf + bh * SS * HD;
  const unsigned short* V = vt + bh * HD * SS;   // [hd][s]

  __shared__ __align__(16) unsigned short Klds[2][64 * 64];
  __shared__ __align__(16) unsigned short Vlds[2][64 * 64];

  const int srow = tid >> 3, scol = tid & 7;
  const int sK_w = ((srow & 3) << 1) | ((srow >> 4) & 1);
  const int sV_w = ((srow & 3) << 1) | ((srow >> 2) & 1);
  const int kdst = srow * 64 + ((scol ^ sK_w) * 8);
  const int vdst = srow * 64 + ((scol ^ sV_w) * 8);
  const unsigned short* Kg0 = K + (size_t)srow * HD + scol * 8;
  const unsigned short* Vg0 = V + (size_t)srow * SS + scol * 8;

  int kaoff[4][2], vaoff[4][2];
#pragma unroll
  for (int ni = 0; ni < 4; ni++) {
    int r = (c >> 2) * 16 + ni * 4 + (c & 3);
    int s = ((r & 3) << 1) | ((r >> 4) & 1);
#pragma unroll
    for (int kk = 0; kk < 2; kk++)
      kaoff[ni][kk] = r * 64 + (((kk * 4 + g) ^ s) * 8);
  }
#pragma unroll
  for (int nh = 0; nh < 4; nh++) {
    int r = nh * 16 + c;
    int s = ((r & 3) << 1) | ((r >> 2) & 1);
#pragma unroll
    for (int k2 = 0; k2 < 2; k2++)
      vaoff[nh][k2] = r * 64 + (((2 * g + k2) ^ s) * 8);
  }

  const int q0 = qtB * 256 + w * 32;
  const int nt = 4 * qtB + 4;
  const int ntw = q0 / 64 + 1;

  bf16x8 aq[2][2];
#pragma unroll
  for (int qf = 0; qf < 2; qf++)
#pragma unroll
    for (int kk = 0; kk < 2; kk++)
      aq[qf][kk] = *(const bf16x8*)&Q[(size_t)(q0 + qf * 16 + c) * HD + kk * 32 + g * 8];

  float l_run[2] = {0.f, 0.f};
  f32x4 acc[2][4];
#pragma unroll
  for (int qf = 0; qf < 2; qf++)
#pragma unroll
    for (int nh = 0; nh < 4; nh++) acc[qf][nh] = (f32x4){0.f, 0.f, 0.f, 0.f};

  {   // prologue: stage tile 0
    uint4 k0 = *(const uint4*)Kg0;
    uint4 v0 = *(const uint4*)Vg0;
    __syncthreads();
    *(uint4*)&Klds[0][kdst] = k0;
    *(uint4*)&Vlds[0][vdst] = v0;
    __syncthreads();
  }
  int cur = 0;

#pragma unroll 1
  for (int t = 0; t < nt; ++t) {
    const bool more = (t + 1 < nt);
    uint4 knx, vnx;
    if (more) {
      knx = *(const uint4*)(Kg0 + (size_t)(t + 1) * 64 * HD);
      vnx = *(const uint4*)(Vg0 + (t + 1) * 64);
    }
    if (t < ntw) {
      const unsigned short* Kl = Klds[cur];
      const unsigned short* Vl = Vlds[cur];
      bf16x8 ka[4][2], va[4][2];
#pragma unroll
      for (int ni = 0; ni < 4; ni++)
#pragma unroll
        for (int kk = 0; kk < 2; kk++)
          ka[ni][kk] = *(const bf16x8*)&Kl[kaoff[ni][kk]];
#pragma unroll
      for (int nh = 0; nh < 4; nh++)
#pragma unroll
        for (int k2 = 0; k2 < 2; k2++)
          va[nh][k2] = *(const bf16x8*)&Vl[vaoff[nh][k2]];

      // S^T = K Q^T: reg jj of frag ni -> kv = t*64 + 16g + 4ni + jj, q = q0+qf*16+c
      f32x4 sv[2][4];
      __builtin_amdgcn_s_setprio(1);
#pragma unroll
      for (int qf = 0; qf < 2; qf++)
#pragma unroll
        for (int ni = 0; ni < 4; ni++) {
          f32x4 z = (f32x4){0.f, 0.f, 0.f, 0.f};
          z = __builtin_amdgcn_mfma_f32_16x16x32_bf16(ka[ni][0], aq[qf][0], z, 0, 0, 0);
          sv[qf][ni] = __builtin_amdgcn_mfma_f32_16x16x32_bf16(ka[ni][1], aq[qf][1], z, 0, 0, 0);
        }
      __builtin_amdgcn_s_setprio(0);

      if (t == ntw - 1) {   // diagonal tile: causal mask
#pragma unroll
        for (int qf = 0; qf < 2; qf++) {
          int q = q0 + qf * 16 + c;
#pragma unroll
          for (int ni = 0; ni < 4; ni++)
#pragma unroll
            for (int jj = 0; jj < 4; jj++) {
              int kvv = t * 64 + g * 16 + ni * 4 + jj;
              if (kvv > q) sv[qf][ni][jj] = -3.0e38f;
            }
        }
      }

#pragma unroll
      for (int qf = 0; qf < 2; qf++) {
        // fixed-offset softmax: no cross-lane dependency before exp2
        float rs = 0.f;
#pragma unroll
        for (int ni = 0; ni < 4; ni++)
#pragma unroll
          for (int jj = 0; jj < 4; jj++) {
            float p = exp2f(sv[qf][ni][jj] - 16.0f);
            sv[qf][ni][jj] = p;
            rs += p;
          }

        union { unsigned int u[4]; bf16x8 v; } pb0, pb1;
        pb0.u[0] = cvt_pk_bf16(sv[qf][0][0], sv[qf][0][1]);
        pb0.u[1] = cvt_pk_bf16(sv[qf][0][2], sv[qf][0][3]);
        pb0.u[2] = cvt_pk_bf16(sv[qf][1][0], sv[qf][1][1]);
        pb0.u[3] = cvt_pk_bf16(sv[qf][1][2], sv[qf][1][3]);
        pb1.u[0] = cvt_pk_bf16(sv[qf][2][0], sv[qf][2][1]);
        pb1.u[1] = cvt_pk_bf16(sv[qf][2][2], sv[qf][2][3]);
        pb1.u[2] = cvt_pk_bf16(sv[qf][3][0], sv[qf][3][1]);
        pb1.u[3] = cvt_pk_bf16(sv[qf][3][2], sv[qf][3][3]);

        __builtin_amdgcn_s_setprio(1);
#pragma unroll
        for (int nh = 0; nh < 4; nh++) {
          acc[qf][nh] = __builtin_amdgcn_mfma_f32_16x16x32_bf16(va[nh][0], pb0.v, acc[qf][nh], 0, 0, 0);
          acc[qf][nh] = __builtin_amdgcn_mfma_f32_16x16x32_bf16(va[nh][1], pb1.v, acc[qf][nh], 0, 0, 0);
        }
        __builtin_amdgcn_s_setprio(0);

        // l-sum reduce off the critical path (PV already issued)
        rs += __shfl_xor(rs, 16);
        rs += __shfl_xor(rs, 32);
        l_run[qf] += rs;
      }
    }
    if (more) {
      *(uint4*)&Klds[cur ^ 1][kdst] = knx;
      *(uint4*)&Vlds[cur ^ 1][vdst] = vnx;
      __syncthreads();
      cur ^= 1;
    }
  }

#pragma unroll
  for (int qf = 0; qf < 2; qf++) {
    float inv = 1.0f / l_run[qf];
    size_t rowoff = ((size_t)b * SS + q0 + qf * 16 + c) * DOUT + h * HD;
#pragma unroll
    for (int nh = 0; nh < 4; nh++) {
      uint2 st;
      st.x = cvt_pk_bf16(acc[qf][nh][0] * inv, acc[qf][nh][1] * inv);
      st.y = cvt_pk_bf16(acc[qf][nh][2] * inv, acc[qf][nh][3] * inv);
      *(uint2*)&ctx[rowoff + nh * 16 + g * 4] = st;
    }
  }
}

// ---------------- launch ----------------

extern "C" void kernel_launch(void* const* d_in, const int* in_sizes, int n_in,
                              void* d_out, int out_size, void* d_ws, size_t ws_size,
                              hipStream_t stream) {
  const float* x  = (const float*)d_in[0];
  const float* Wq = (const float*)d_in[1];
  const float* Wk = (const float*)d_in[2];
  const float* Wv = (const float*)d_in[3];
  const float* Wp = (const float*)d_in[4];
  const float* bp = (const float*)d_in[5];
  float* out = (float*)d_out;

  unsigned short* ws = (unsigned short*)d_ws;
  unsigned short* xb = ws;                      // 8388608 elems (x bf16; later reused as ctx)
  unsigned short* wt = xb + (size_t)MROWS * DIN;       // 4 * 1048576 (Wq^T,Wk^T,Wv^T,Wp^T)
  unsigned short* qs = wt + (size_t)4 * DIN * DOUT;    // 8388608 (Q scaled, [b][h][s][hd])
  unsigned short* kb = qs + (size_t)MROWS * DOUT;      // 8388608 ([b][h][s][hd])
  unsigned short* vt = kb + (size_t)MROWS * DOUT;      // 8388608 ([b][h][hd][s])
  unsigned short* ctx = xb;                            // alias: x dead after projections

  const int kLds = 32 * 1024;   // BK=32 double-buffer -> ~5 blocks/CU
  (void)hipFuncSetAttribute((const void*)gemm_qkv_kernel,
                            hipFuncAttributeMaxDynamicSharedMemorySize, kLds);
  (void)hipFuncSetAttribute((const void*)gemm_out_kernel,
                            hipFuncAttributeMaxDynamicSharedMemorySize, kLds);

  cvt_fused_kernel<<<6144, 256, 0, stream>>>(x, Wq, Wk, Wv, Wp, xb, wt);
  gemm_qkv_kernel<<<dim3(8, 64, 3), 256, kLds, stream>>>(xb, wt, qs, kb, vt);
  attn_kernel<<<512, 512, 0, stream>>>(qs, kb, vt, ctx);
  gemm_out_kernel<<<dim3(8, 64), 256, kLds, stream>>>(ctx, wt + (size_t)3 * DIN * DOUT, bp, out);
}

// Round 21
// 157.984 us; speedup vs baseline: 1.0782x; 1.0782x over previous
//
#include <hip/hip_runtime.h>
#include <hip/hip_bf16.h>
#include <stdint.h>

// Problem constants
#define BB   4
#define SS   2048
#define DIN  1024
#define DOUT 1024
#define NH   16
#define HD   64
#define MROWS (BB * SS)   // 8192

typedef __bf16 bf16x8 __attribute__((ext_vector_type(8)));
typedef float  f32x4  __attribute__((ext_vector_type(4)));

__device__ __forceinline__ unsigned short f2bf(float f) {
  union { float f; uint32_t u; } v; v.f = f;
  uint32_t u = v.u;
  uint32_t r = (u + 0x7fffu + ((u >> 16) & 1u)) >> 16;
  return (unsigned short)r;
}

__device__ __forceinline__ unsigned int cvt_pk_bf16(float lo, float hi) {
  unsigned int r;
  asm("v_cvt_pk_bf16_f32 %0, %1, %2" : "=v"(r) : "v"(lo), "v"(hi));
  return r;
}

#define GLOAD_LDS16(gsrc, ldst)                                                   \
  __builtin_amdgcn_global_load_lds(                                               \
      (const __attribute__((address_space(1))) void*)(gsrc),                      \
      (__attribute__((address_space(3))) void*)(ldst), 16, 0, 0)

// ---------------- fused conversion kernel ----------------
// blocks [0,2048): x f32 -> bf16 (4 float4 per thread, coalesced)
// blocks [2048,6144): W transpose-convert, one 32x32 tile per block.
__global__ __launch_bounds__(256) void cvt_fused_kernel(
    const float* __restrict__ x,
    const float* __restrict__ w0, const float* __restrict__ w1,
    const float* __restrict__ w2, const float* __restrict__ w3,
    unsigned short* __restrict__ xb, unsigned short* __restrict__ wt) {
  __shared__ float tile[32][33];
  const int bx = blockIdx.x, tid = threadIdx.x;
  if (bx < 2048) {
    const float4* in4 = (const float4*)x;
    ushort4* out4 = (ushort4*)xb;
    int i = bx * 256 + tid;
#pragma unroll
    for (int r = 0; r < 4; ++r) {
      int idx = i + r * (2048 * 256);   // covers 2,097,152 float4 total
      float4 f = in4[idx];
      ushort4 o;
      o.x = f2bf(f.x); o.y = f2bf(f.y); o.z = f2bf(f.z); o.w = f2bf(f.w);
      out4[idx] = o;
    }
  } else {
    const int t = bx - 2048;          // 0..4095
    const int z = t >> 10;            // matrix 0..3
    const int tt = t & 1023;          // tile 0..1023
    const int kb = (tt & 31) * 32, nb = (tt >> 5) * 32;
    const float* src = (z == 0) ? w0 : (z == 1) ? w1 : (z == 2) ? w2 : w3;
    unsigned short* dst = wt + (size_t)z * (DIN * DOUT);
    const int row0 = tid >> 5, col = tid & 31;
#pragma unroll
    for (int r = 0; r < 4; ++r) {
      int row = row0 + r * 8;
      tile[row][col] = src[(size_t)(kb + row) * DOUT + nb + col];
    }
    __syncthreads();
#pragma unroll
    for (int r = 0; r < 4; ++r) {
      int row = row0 + r * 8;
      dst[(size_t)(nb + row) * DIN + kb + col] = f2bf(tile[col][row]);
    }
  }
}

// XCD-aware bijective remap for 512-block GEMM grids (8 XCDs, 512 = 8*64)
__device__ __forceinline__ void xcd_remap_512(int& nT, int& mT) {
  int orig = blockIdx.x + blockIdx.y * 8;
  int id = (orig & 7) * 64 + (orig >> 3);
  nT = id & 7;
  mT = id >> 3;
}

// ---------------- GEMM core: 128x128 tile, BK=64, dbuf 64KB, 2 blocks/CU ----
// (round 8 -- co-residency pipelining, conflict-free swizzle)
__device__ __forceinline__ void gemm128_core(const unsigned short* __restrict__ A,
                                             const unsigned short* __restrict__ BT,
                                             f32x4 (&acc)[4][4]) {
  extern __shared__ __align__(16) unsigned short sm[];
  const int tid = threadIdx.x, lane = tid & 63, w = tid >> 6;
  const int wm = (w >> 1) * 64, wn = (w & 1) * 64;
  const int g = lane >> 4, c = lane & 15;

#pragma unroll
  for (int mi = 0; mi < 4; mi++)
#pragma unroll
    for (int ni = 0; ni < 4; ni++)
      acc[mi][ni] = (f32x4){0.f, 0.f, 0.f, 0.f};

  const int srow = tid >> 3;
  const int gchunk = (tid & 7) ^ (srow & 7);
  const unsigned short* Ag = A + (size_t)srow * 1024 + gchunk * 8;
  const unsigned short* Bg = BT + (size_t)srow * 1024 + gchunk * 8;
  const int dst8 = tid * 8;

#define STAGE128(kt, buf) do {                                              \
    const int _k = (kt) * 64;                                               \
    _Pragma("unroll") for (int _j = 0; _j < 4; ++_j) {                      \
      GLOAD_LDS16(Ag + (size_t)_j * 32 * 1024 + _k,                         \
                  &sm[(buf) * 8192 + _j * 2048 + dst8]);                    \
      GLOAD_LDS16(Bg + (size_t)_j * 32 * 1024 + _k,                         \
                  &sm[16384 + (buf) * 8192 + _j * 2048 + dst8]);            \
    } } while (0)

  int aoff[4][2], boff[4][2];
#pragma unroll
  for (int mi = 0; mi < 4; mi++)
#pragma unroll
    for (int k2 = 0; k2 < 2; k2++)
      aoff[mi][k2] = (wm + mi * 16 + c) * 64 + (((k2 * 4 + g) ^ (c & 7)) * 8);
#pragma unroll
  for (int ni = 0; ni < 4; ni++)
#pragma unroll
    for (int k2 = 0; k2 < 2; k2++)
      boff[ni][k2] = (wn + ni * 16 + c) * 64 + (((k2 * 4 + g) ^ (c & 7)) * 8);

  STAGE128(0, 0);
  __syncthreads();

#pragma unroll 1
  for (int t = 0; t < 16; ++t) {
    const int buf = t & 1;
    if (t + 1 < 16) STAGE128(t + 1, buf ^ 1);
    const unsigned short* As_ = sm + buf * 8192;
    const unsigned short* Bs_ = sm + 16384 + buf * 8192;
#pragma unroll
    for (int k2 = 0; k2 < 2; k2++) {
      bf16x8 a[4], b[4];
#pragma unroll
      for (int mi = 0; mi < 4; mi++) a[mi] = *(const bf16x8*)&As_[aoff[mi][k2]];
#pragma unroll
      for (int ni = 0; ni < 4; ni++) b[ni] = *(const bf16x8*)&Bs_[boff[ni][k2]];
#pragma unroll
      for (int mi = 0; mi < 4; mi++)
#pragma unroll
        for (int ni = 0; ni < 4; ni++)
          acc[mi][ni] = __builtin_amdgcn_mfma_f32_16x16x32_bf16(a[mi], b[ni], acc[mi][ni], 0, 0, 0);
    }
    __syncthreads();
  }
#undef STAGE128
}

// QKV projection. z=0: Q (scaled log2e/8) -> [b][h][s][hd]; z=1: K; z=2: V^T [b][h][hd][s]
__global__ __launch_bounds__(256, 2) void gemm_qkv_kernel(
    const unsigned short* __restrict__ xb, const unsigned short* __restrict__ wt,
    unsigned short* __restrict__ qs, unsigned short* __restrict__ kbuf,
    unsigned short* __restrict__ vt) {
  int nT, mT;
  xcd_remap_512(nT, mT);
  const int z = blockIdx.z;
  f32x4 acc[4][4];
  gemm128_core(xb + (size_t)mT * 128 * 1024,
               wt + (size_t)z * (DIN * DOUT) + (size_t)nT * 128 * 1024, acc);

  const int tid = threadIdx.x, lane = tid & 63, w = tid >> 6;
  const int wm = (w >> 1) * 64, wn = (w & 1) * 64;
  const int g = lane >> 4, c = lane & 15;
  const float scale = (z == 0) ? 0.18033688011112042f : 1.0f;  // (1/8)*log2(e)

  if (z < 2) {
    unsigned short* dstQK = (z == 0) ? qs : kbuf;
#pragma unroll
    for (int mi = 0; mi < 4; mi++)
#pragma unroll
      for (int ni = 0; ni < 4; ni++) {
        int n = nT * 128 + wn + ni * 16 + c;
        int h = n >> 6, hd = n & 63;
#pragma unroll
        for (int jj = 0; jj < 4; jj++) {
          int m = mT * 128 + wm + mi * 16 + g * 4 + jj;
          int b = m >> 11, ss = m & 2047;
          dstQK[(((size_t)(b * NH + h)) * SS + ss) * HD + hd] = f2bf(acc[mi][ni][jj] * scale);
        }
      }
  } else {
#pragma unroll
    for (int mi = 0; mi < 4; mi++) {
      int m0 = mT * 128 + wm + mi * 16 + g * 4;
      int b = m0 >> 11, s0 = m0 & 2047;
#pragma unroll
      for (int ni = 0; ni < 4; ni++) {
        int n = nT * 128 + wn + ni * 16 + c;
        int h = n >> 6, hd = n & 63;
        uint2 st;
        st.x = cvt_pk_bf16(acc[mi][ni][0], acc[mi][ni][1]);
        st.y = cvt_pk_bf16(acc[mi][ni][2], acc[mi][ni][3]);
        *(uint2*)&vt[(((size_t)(b * NH + h)) * HD + hd) * SS + s0] = st;
      }
    }
  }
}

// Output projection: out = ctx @ Wp + bp (fp32 out)
__global__ __launch_bounds__(256, 2) void gemm_out_kernel(
    const unsigned short* __restrict__ ctx, const unsigned short* __restrict__ wtp,
    const float* __restrict__ bp, float* __restrict__ out) {
  int nT, mT;
  xcd_remap_512(nT, mT);
  f32x4 acc[4][4];
  gemm128_core(ctx + (size_t)mT * 128 * 1024, wtp + (size_t)nT * 128 * 1024, acc);

  const int tid = threadIdx.x, lane = tid & 63, w = tid >> 6;
  const int wm = (w >> 1) * 64, wn = (w & 1) * 64;
  const int g = lane >> 4, c = lane & 15;
#pragma unroll
  for (int mi = 0; mi < 4; mi++)
#pragma unroll
    for (int ni = 0; ni < 4; ni++) {
      int n = nT * 128 + wn + ni * 16 + c;
      float bias = bp[n];
#pragma unroll
      for (int jj = 0; jj < 4; jj++) {
        int m = mT * 128 + wm + mi * 16 + g * 4 + jj;
        out[(size_t)m * DOUT + n] = acc[mi][ni][jj] + bias;
      }
    }
}

// ---------------- flash attention: 8-wave blocks, 1 q-block each ------------
// ROUND-15 EXACT (field-proven: passed, 82 us, absmax 0.015625). FROZEN.
__global__ __launch_bounds__(512) void attn_kernel(
    const unsigned short* __restrict__ qs, const unsigned short* __restrict__ kbuf,
    const unsigned short* __restrict__ vt, unsigned short* __restrict__ ctx) {
  const int bx = blockIdx.x;
  const int xcd = bx & 7, j = bx >> 3;
  const int hb = xcd * 8 + (j & 7);
  const int h = hb & 15, b = hb >> 4;
  const int qtB = 7 - (j >> 3);

  const int tid = threadIdx.x, lane = tid & 63, w = tid >> 6;
  const int g = lane >> 4, c = lane & 15;
  const size_t bh = (size_t)(b * NH + h);
  const unsigned short* Q = qs + bh * SS * HD;
  const unsigned short* K = kbuf + bh * SS * HD;
  const unsigned short* V = vt + bh * HD * SS;   // [hd][s]

  __shared__ __align__(16) unsigned short Klds[2][64 * 64];
  __shared__ __align__(16) unsigned short Vlds[2][64 * 64];

  const int srow = tid >> 3, scol = tid & 7;
  const int sK_w = ((srow & 3) << 1) | ((srow >> 4) & 1);
  const int sV_w = ((srow & 3) << 1) | ((srow >> 2) & 1);
  const int kdst = srow * 64 + ((scol ^ sK_w) * 8);
  const int vdst = srow * 64 + ((scol ^ sV_w) * 8);
  const unsigned short* Kg0 = K + (size_t)srow * HD + scol * 8;
  const unsigned short* Vg0 = V + (size_t)srow * SS + scol * 8;

  int kaoff[4][2], vaoff[4][2];
#pragma unroll
  for (int ni = 0; ni < 4; ni++) {
    int r = (c >> 2) * 16 + ni * 4 + (c & 3);
    int s = ((r & 3) << 1) | ((r >> 4) & 1);
#pragma unroll
    for (int kk = 0; kk < 2; kk++)
      kaoff[ni][kk] = r * 64 + (((kk * 4 + g) ^ s) * 8);
  }
#pragma unroll
  for (int nh = 0; nh < 4; nh++) {
    int r = nh * 16 + c;
    int s = ((r & 3) << 1) | ((r >> 2) & 1);
#pragma unroll
    for (int k2 = 0; k2 < 2; k2++)
      vaoff[nh][k2] = r * 64 + (((2 * g + k2) ^ s) * 8);
  }

  const int q0 = qtB * 256 + w * 32;
  const int nt = 4 * qtB + 4;
  const int ntw = q0 / 64 + 1;

  bf16x8 aq[2][2];
#pragma unroll
  for (int qf = 0; qf < 2; qf++)
#pragma unroll
    for (int kk = 0; kk < 2; kk++)
      aq[qf][kk] = *(const bf16x8*)&Q[(size_t)(q0 + qf * 16 + c) * HD + kk * 32 + g * 8];

  float l_run[2] = {0.f, 0.f};
  f32x4 acc[2][4];
#pragma unroll
  for (int qf = 0; qf < 2; qf++)
#pragma unroll
    for (int nh = 0; nh < 4; nh++) acc[qf][nh] = (f32x4){0.f, 0.f, 0.f, 0.f};

  {   // prologue: stage tile 0
    uint4 k0 = *(const uint4*)Kg0;
    uint4 v0 = *(const uint4*)Vg0;
    __syncthreads();
    *(uint4*)&Klds[0][kdst] = k0;
    *(uint4*)&Vlds[0][vdst] = v0;
    __syncthreads();
  }
  int cur = 0;

#pragma unroll 1
  for (int t = 0; t < nt; ++t) {
    const bool more = (t + 1 < nt);
    uint4 knx, vnx;
    if (more) {
      knx = *(const uint4*)(Kg0 + (size_t)(t + 1) * 64 * HD);
      vnx = *(const uint4*)(Vg0 + (t + 1) * 64);
    }
    if (t < ntw) {
      const unsigned short* Kl = Klds[cur];
      const unsigned short* Vl = Vlds[cur];
      bf16x8 ka[4][2], va[4][2];
#pragma unroll
      for (int ni = 0; ni < 4; ni++)
#pragma unroll
        for (int kk = 0; kk < 2; kk++)
          ka[ni][kk] = *(const bf16x8*)&Kl[kaoff[ni][kk]];
#pragma unroll
      for (int nh = 0; nh < 4; nh++)
#pragma unroll
        for (int k2 = 0; k2 < 2; k2++)
          va[nh][k2] = *(const bf16x8*)&Vl[vaoff[nh][k2]];

      // S^T = K Q^T: reg jj of frag ni -> kv = t*64 + 16g + 4ni + jj, q = q0+qf*16+c
      f32x4 sv[2][4];
      __builtin_amdgcn_s_setprio(1);
#pragma unroll
      for (int qf = 0; qf < 2; qf++)
#pragma unroll
        for (int ni = 0; ni < 4; ni++) {
          f32x4 z = (f32x4){0.f, 0.f, 0.f, 0.f};
          z = __builtin_amdgcn_mfma_f32_16x16x32_bf16(ka[ni][0], aq[qf][0], z, 0, 0, 0);
          sv[qf][ni] = __builtin_amdgcn_mfma_f32_16x16x32_bf16(ka[ni][1], aq[qf][1], z, 0, 0, 0);
        }
      __builtin_amdgcn_s_setprio(0);

      if (t == ntw - 1) {   // diagonal tile: causal mask
#pragma unroll
        for (int qf = 0; qf < 2; qf++) {
          int q = q0 + qf * 16 + c;
#pragma unroll
          for (int ni = 0; ni < 4; ni++)
#pragma unroll
            for (int jj = 0; jj < 4; jj++) {
              int kvv = t * 64 + g * 16 + ni * 4 + jj;
              if (kvv > q) sv[qf][ni][jj] = -3.0e38f;
            }
        }
      }

#pragma unroll
      for (int qf = 0; qf < 2; qf++) {
        // fixed-offset softmax: no cross-lane dependency before exp2
        float rs = 0.f;
#pragma unroll
        for (int ni = 0; ni < 4; ni++)
#pragma unroll
          for (int jj = 0; jj < 4; jj++) {
            float p = exp2f(sv[qf][ni][jj] - 16.0f);
            sv[qf][ni][jj] = p;
            rs += p;
          }

        union { unsigned int u[4]; bf16x8 v; } pb0, pb1;
        pb0.u[0] = cvt_pk_bf16(sv[qf][0][0], sv[qf][0][1]);
        pb0.u[1] = cvt_pk_bf16(sv[qf][0][2], sv[qf][0][3]);
        pb0.u[2] = cvt_pk_bf16(sv[qf][1][0], sv[qf][1][1]);
        pb0.u[3] = cvt_pk_bf16(sv[qf][1][2], sv[qf][1][3]);
        pb1.u[0] = cvt_pk_bf16(sv[qf][2][0], sv[qf][2][1]);
        pb1.u[1] = cvt_pk_bf16(sv[qf][2][2], sv[qf][2][3]);
        pb1.u[2] = cvt_pk_bf16(sv[qf][3][0], sv[qf][3][1]);
        pb1.u[3] = cvt_pk_bf16(sv[qf][3][2], sv[qf][3][3]);

        __builtin_amdgcn_s_setprio(1);
#pragma unroll
        for (int nh = 0; nh < 4; nh++) {
          acc[qf][nh] = __builtin_amdgcn_mfma_f32_16x16x32_bf16(va[nh][0], pb0.v, acc[qf][nh], 0, 0, 0);
          acc[qf][nh] = __builtin_amdgcn_mfma_f32_16x16x32_bf16(va[nh][1], pb1.v, acc[qf][nh], 0, 0, 0);
        }
        __builtin_amdgcn_s_setprio(0);

        // l-sum reduce off the critical path (PV already issued)
        rs += __shfl_xor(rs, 16);
        rs += __shfl_xor(rs, 32);
        l_run[qf] += rs;
      }
    }
    if (more) {
      *(uint4*)&Klds[cur ^ 1][kdst] = knx;
      *(uint4*)&Vlds[cur ^ 1][vdst] = vnx;
      __syncthreads();
      cur ^= 1;
    }
  }

#pragma unroll
  for (int qf = 0; qf < 2; qf++) {
    float inv = 1.0f / l_run[qf];
    size_t rowoff = ((size_t)b * SS + q0 + qf * 16 + c) * DOUT + h * HD;
#pragma unroll
    for (int nh = 0; nh < 4; nh++) {
      uint2 st;
      st.x = cvt_pk_bf16(acc[qf][nh][0] * inv, acc[qf][nh][1] * inv);
      st.y = cvt_pk_bf16(acc[qf][nh][2] * inv, acc[qf][nh][3] * inv);
      *(uint2*)&ctx[rowoff + nh * 16 + g * 4] = st;
    }
  }
}

// ---------------- launch ----------------

extern "C" void kernel_launch(void* const* d_in, const int* in_sizes, int n_in,
                              void* d_out, int out_size, void* d_ws, size_t ws_size,
                              hipStream_t stream) {
  const float* x  = (const float*)d_in[0];
  const float* Wq = (const float*)d_in[1];
  const float* Wk = (const float*)d_in[2];
  const float* Wv = (const float*)d_in[3];
  const float* Wp = (const float*)d_in[4];
  const float* bp = (const float*)d_in[5];
  float* out = (float*)d_out;

  unsigned short* ws = (unsigned short*)d_ws;
  unsigned short* xb = ws;                      // 8388608 elems (x bf16; later reused as ctx)
  unsigned short* wt = xb + (size_t)MROWS * DIN;       // 4 * 1048576 (Wq^T,Wk^T,Wv^T,Wp^T)
  unsigned short* qs = wt + (size_t)4 * DIN * DOUT;    // 8388608 (Q scaled, [b][h][s][hd])
  unsigned short* kb = qs + (size_t)MROWS * DOUT;      // 8388608 ([b][h][s][hd])
  unsigned short* vt = kb + (size_t)MROWS * DOUT;      // 8388608 ([b][h][hd][s])
  unsigned short* ctx = xb;                            // alias: x dead after projections

  const int kLds = 64 * 1024;   // BK=64 double-buffer -> 2 blocks/CU
  (void)hipFuncSetAttribute((const void*)gemm_qkv_kernel,
                            hipFuncAttributeMaxDynamicSharedMemorySize, kLds);
  (void)hipFuncSetAttribute((const void*)gemm_out_kernel,
                            hipFuncAttributeMaxDynamicSharedMemorySize, kLds);

  cvt_fused_kernel<<<6144, 256, 0, stream>>>(x, Wq, Wk, Wv, Wp, xb, wt);
  gemm_qkv_kernel<<<dim3(8, 64, 3), 256, kLds, stream>>>(xb, wt, qs, kb, vt);
  attn_kernel<<<512, 512, 0, stream>>>(qs, kb, vt, ctx);
  gemm_out_kernel<<<dim3(8, 64), 256, kLds, stream>>>(ctx, wt + (size_t)3 * DIN * DOUT, bp, out);
}